// Round 12
// baseline (829.893 us; speedup 1.0000x reference)
//
#include <hip/hip_runtime.h>

// out[8192,4096] = x[8192,4096] @ (q[4096,4096]*scale)^T
// INT8 path (R7/R8-proven, absmax 216): per-row quant x -> i8, exact i8
// weights, mfma_i32_16x16x64_i8, fp32 epilogue scale.
// R12 = R8's reg-prefetch discipline x R6's 2-blocks/CU occupancy:
//   tile 128x256, BK=64, ring-3 slots (A 8KB + B 16KB = 24KB/slot, 72 KiB)
//   -> 2 blocks/CU; cross-tile register prefetch (MFMA consumes frags read
//   during the previous body -> no intra-phase read->MFMA dependency);
//   stage distance 2, counted vmcnt(3); proven kx swizzle (0 conflicts).

typedef __attribute__((ext_vector_type(4))) int int4v;
typedef __attribute__((ext_vector_type(4))) float float4v;

constexpr int Mdim = 8192, Ndim = 4096, Kdim = 4096;
constexpr int BM = 128, BN = 256, BK = 64;
constexpr int NT_N = Ndim / BN;                 // 16
constexpr int NWG = (Mdim / BM) * (Ndim / BN);  // 64*16 = 1024 (%8==0)
constexpr int NTILES = Kdim / BK;               // 64
constexpr int SLOT_BYTES = (BM + BN) * BK;      // 24576

#define GLOAD16(gp, lp)                                                      \
  __builtin_amdgcn_global_load_lds(                                          \
      (const __attribute__((address_space(1))) void*)(gp),                   \
      (__attribute__((address_space(3))) void*)(lp), 16, 0, 0)
#define FENCE() asm volatile("" ::: "memory")
#define BARRIER()                      \
  do {                                 \
    FENCE();                           \
    __builtin_amdgcn_s_barrier();      \
    FENCE();                           \
  } while (0)
#define WAIT_VM(n) asm volatile("s_waitcnt vmcnt(" #n ")" ::: "memory")

// ---- x -> i8, per-row scale ------------------------------------------------
__global__ void quant_x_i8(const float* __restrict__ x,
                           signed char* __restrict__ xq,
                           float* __restrict__ sr) {
  const int row = blockIdx.x;
  const int t = threadIdx.x;  // 256 threads, 16 floats each
  const float4v* px = (const float4v*)(x + (size_t)row * Kdim);
  float4v v[4];
  float am = 0.f;
#pragma unroll
  for (int i = 0; i < 4; ++i) {
    v[i] = px[t * 4 + i];
#pragma unroll
    for (int j = 0; j < 4; ++j) am = fmaxf(am, fabsf(v[i][j]));
  }
#pragma unroll
  for (int off = 32; off; off >>= 1) am = fmaxf(am, __shfl_xor(am, off));
  __shared__ float wmx[4];
  if ((t & 63) == 0) wmx[t >> 6] = am;
  __syncthreads();
  am = fmaxf(fmaxf(wmx[0], wmx[1]), fmaxf(wmx[2], wmx[3]));
  const float rcp = am > 0.f ? 127.0f / am : 0.f;
  if (t == 0) sr[row] = am * (1.0f / 127.0f);
  int o[4];
#pragma unroll
  for (int i = 0; i < 4; ++i) {
    int q0 = __float2int_rn(v[i][0] * rcp);
    int q1 = __float2int_rn(v[i][1] * rcp);
    int q2 = __float2int_rn(v[i][2] * rcp);
    int q3 = __float2int_rn(v[i][3] * rcp);
    o[i] = (q0 & 255) | ((q1 & 255) << 8) | ((q2 & 255) << 16) | (q3 << 24);
  }
  int4v ov = {o[0], o[1], o[2], o[3]};
  ((int4v*)(xq + (size_t)row * Kdim))[t] = ov;
}

// ---- q (int32 codes 0..126) -> i8 ------------------------------------------
__global__ void cvt_q_i8(const int* __restrict__ q,
                         signed char* __restrict__ qq, int n16) {
  int i = blockIdx.x * blockDim.x + threadIdx.x;
  const int stride = gridDim.x * blockDim.x;
  for (; i < n16; i += stride) {
    const int4v* p = (const int4v*)q + i * 4;
    int o[4];
#pragma unroll
    for (int k = 0; k < 4; ++k) {
      int4v w = p[k];
      o[k] = w[0] | (w[1] << 8) | (w[2] << 16) | (w[3] << 24);
    }
    int4v ov = {o[0], o[1], o[2], o[3]};
    ((int4v*)qq)[i] = ov;
  }
}

// ---- 128x256 i8 GEMM, ring-3 + reg-prefetch: C = (A*B^T)*srow*wscale -------
// LDS slot: A rows 0..127 at [0, 8K), B rows 0..255 at [8K, 24K). 64 B rows.
// Swizzle (R7/R8-proven, 0 conflicts): read col kx = (kg^((fr>>1)&3))<<4;
// staged via linear DMA dest + pre-swizzled global source (rule #21).
//
// Body u (one barrier per tile):
//   rd b(u+1), a(u+1) (slot (u+1)%3) -> NXT regs   [RAW: forced by vmcnt(3)
//     at end of body u-1 + barrier]
//   stage3 tile min(u+2,63) -> slot (u+2)%3        [WAR: last read body u-2,
//     >=2 barriers back]
//   16 MFMA on CUR regs (read during body u-1 -> no dependency on this
//     body's ds_reads; compiler emits counted lgkm)
//   vmcnt(3)  [outstanding stage(u+1)+stage(u+2)=6 -> forces stage(u+1)]
//   barrier
__global__ __launch_bounds__(512, 4) void gemm_i8(
    const signed char* __restrict__ A, const signed char* __restrict__ B,
    float* __restrict__ C, const float* __restrict__ srow,
    const float* __restrict__ scale_p) {
  __shared__ signed char sS[3][SLOT_BYTES];  // 72 KiB -> 2 blocks/CU

  const int tid = threadIdx.x;
  const int wid = tid >> 6, lane = tid & 63;
  const int fr = lane & 15;
  const int kg = lane >> 4;
  const int kx = ((kg ^ ((fr >> 1) & 3)) << 4);  // swizzled 16-B slot

  const int bid = blockIdx.x;
  const int swz = (bid & 7) * (NWG / 8) + (bid >> 3);
  const int mt = swz / NT_N, ntl = swz % NT_N;
  const int brow = mt * BM, bcol = ntl * BN;

  const int wm = wid >> 2, wn = wid & 3;  // 2Mx4N, wave tile 64x64

  // Staging: chunk j (0..2) covers slot bytes [j*8192 + tid*16, +16):
  //   row-in-chunk = tid>>2, phys 16B-slot = tid&3,
  //   src col = ((tid&3) ^ ((row>>1)&3))*16 = ((tid&3) ^ ((tid>>3)&3))<<4
  // j=0 -> A rows 0..127; j=1 -> B rows 0..127; j=2 -> B rows 128..255.
  const int strow = tid >> 2;
  const int stcol = (((tid & 3) ^ ((tid >> 3) & 3)) << 4);
  const signed char* g0 = A + (size_t)(brow + strow) * Kdim + stcol;
  const signed char* g1 = B + (size_t)(bcol + strow) * Kdim + stcol;
  const signed char* g2 = B + (size_t)(bcol + 128 + strow) * Kdim + stcol;

  auto stage3 = [&](int slot, int t) {
    GLOAD16(g0 + t * BK, &sS[slot][0 * 8192 + tid * 16 - (tid * 16 - tid * 16)] + 0), (void)0;
    // (expanded below — kept simple)
  };
  (void)stage3;
  auto stage3x = [&](int slot, int t) {
    GLOAD16(g0 + t * BK, &sS[slot][tid * 16]);
    GLOAD16(g1 + t * BK, &sS[slot][8192 + tid * 16]);
    GLOAD16(g2 + t * BK, &sS[slot][16384 + tid * 16]);
  };
  auto loadA4 = [&](int4v* af, int sl) {
#pragma unroll
    for (int m = 0; m < 4; ++m)
      af[m] = *(const int4v*)(const void*)&sS[sl]
                  [(wm * 64 + m * 16 + fr) * BK + kx];
  };
  auto loadB4 = [&](int4v* bf, int sl) {
#pragma unroll
    for (int n = 0; n < 4; ++n)
      bf[n] = *(const int4v*)(const void*)&sS[sl]
                  [8192 + (wn * 64 + n * 16 + fr) * BK + kx];
  };

  int4v acc[4][4] = {};  // [m][n] i32 (64 AGPR); rows brow + wm*64 + m*16

  auto mma16 = [&](const int4v* af, const int4v* bf) {
    __builtin_amdgcn_s_setprio(1);
#pragma unroll
    for (int m = 0; m < 4; ++m)
#pragma unroll
      for (int n = 0; n < 4; ++n)
        acc[m][n] = __builtin_amdgcn_mfma_i32_16x16x64_i8(
            af[m], bf[n], acc[m][n], 0, 0, 0);
    __builtin_amdgcn_s_setprio(0);
  };

  // Even/odd cross-tile prefetch sets (static indexing — rule #20).
  int4v aE[4], bE[4], aO[4], bO[4];

  auto body = [&](int u, const int4v* aC, const int4v* bC, int4v* aN,
                  int4v* bN) {
    const int sn = (u + 1) % 3;
    const int st = (u + 2) % 3;
    const int t2 = (u + 2 < NTILES) ? u + 2 : NTILES - 1;  // clamped tail
    loadB4(bN, sn);
    loadA4(aN, sn);
    stage3x(st, t2);
    mma16(aC, bC);
    WAIT_VM(3);  // forces stage(u+1) (consumed next body); stage(u+2) flies
    BARRIER();
  };

  // Prologue: tiles 0,1 -> slots 0,1; force tile 0; preload E from slot 0.
  stage3x(0, 0);
  stage3x(1, 1);
  WAIT_VM(3);  // slot 0 landed (this wave)
  BARRIER();   // ... all waves
  loadB4(bE, 0);
  loadA4(aE, 0);

  for (int u = 0; u < NTILES; u += 2) {
    body(u, aE, bE, aO, bO);      // tile u:   cur=E, prefetch->O
    body(u + 1, aO, bO, aE, bE);  // tile u+1: cur=O, prefetch->E
  }

  WAIT_VM(0);  // drain clamped trailing stages before exit

  // Epilogue: D layout col=lane&15, row=(lane>>4)*4+j (dtype-independent).
  const float sw = *scale_p;
  const int col0 = bcol + wn * 64 + fr;
  const int rb = (lane >> 4) * 4;
#pragma unroll
  for (int m = 0; m < 4; ++m)
#pragma unroll
    for (int j = 0; j < 4; ++j) {
      const int row = brow + wm * 64 + m * 16 + rb + j;
      const float f = srow[row] * sw;
#pragma unroll
      for (int n = 0; n < 4; ++n)
        C[(size_t)row * Ndim + (col0 + n * 16)] = (float)acc[m][n][j] * f;
    }
}

extern "C" void kernel_launch(void* const* d_in, const int* in_sizes, int n_in,
                              void* d_out, int out_size, void* d_ws,
                              size_t ws_size, hipStream_t stream) {
  const float* x = (const float*)d_in[0];
  const int* q = (const int*)d_in[1];
  const float* scale = (const float*)d_in[2];
  float* out = (float*)d_out;

  signed char* xq = (signed char*)d_ws;                 // 33.5 MB
  signed char* qq = xq + (size_t)Mdim * Kdim;           // 16.8 MB
  float* sr = (float*)(qq + (size_t)Ndim * Kdim);       // 32 KB
  const size_t ws_needed =
      (size_t)Mdim * Kdim + (size_t)Ndim * Kdim + Mdim * sizeof(float);
  if (ws_size < ws_needed) return;

  quant_x_i8<<<Mdim, 256, 0, stream>>>(x, xq, sr);
  cvt_q_i8<<<2048, 256, 0, stream>>>(q, qq, (Ndim * Kdim) / 16);
  gemm_i8<<<NWG, 512, 0, stream>>>(xq, qq, out, sr, scale);
}

// Round 13
// 406.024 us; speedup vs baseline: 2.0440x; 2.0440x over previous
//
#include <hip/hip_runtime.h>

// out[8192,4096] = x[8192,4096] @ (q[4096,4096]*scale)^T
// INT8 path (R7/R8-proven, absmax 216): per-row quant x -> i8, exact i8
// weights, mfma_i32_16x16x64_i8, fp32 epilogue scale.
// R13: NO-LDS GEMM. The hot K-window is L2-resident (~320 KB/XCD << 4 MB)
// and all inputs are L3-resident (50 MB << 256 MB), so frag loads go
// global->reg directly. No LDS => no barriers => waves dephase and the
// m114 MFMA/VMEM wave-overlap engages; frag traffic moves off the
// contended LDS pipe. Reg-double-buffered E/O frag sets: tile u+1's 12
// b128 loads issue before tile u's 32 MFMAs (compiler emits counted vmcnt).

typedef __attribute__((ext_vector_type(4))) int int4v;
typedef __attribute__((ext_vector_type(4))) float float4v;

constexpr int Mdim = 8192, Ndim = 4096, Kdim = 4096;
constexpr int BM = 256, BN = 256, BK = 64;
constexpr int NT_N = Ndim / BN;                 // 16
constexpr int NWG = (Mdim / BM) * (Ndim / BN);  // 512 (%8==0)
constexpr int NTILES = Kdim / BK;               // 64

// ---- x -> i8, per-row scale ------------------------------------------------
__global__ void quant_x_i8(const float* __restrict__ x,
                           signed char* __restrict__ xq,
                           float* __restrict__ sr) {
  const int row = blockIdx.x;
  const int t = threadIdx.x;  // 256 threads, 16 floats each
  const float4v* px = (const float4v*)(x + (size_t)row * Kdim);
  float4v v[4];
  float am = 0.f;
#pragma unroll
  for (int i = 0; i < 4; ++i) {
    v[i] = px[t * 4 + i];
#pragma unroll
    for (int j = 0; j < 4; ++j) am = fmaxf(am, fabsf(v[i][j]));
  }
#pragma unroll
  for (int off = 32; off; off >>= 1) am = fmaxf(am, __shfl_xor(am, off));
  __shared__ float wmx[4];
  if ((t & 63) == 0) wmx[t >> 6] = am;
  __syncthreads();
  am = fmaxf(fmaxf(wmx[0], wmx[1]), fmaxf(wmx[2], wmx[3]));
  const float rcp = am > 0.f ? 127.0f / am : 0.f;
  if (t == 0) sr[row] = am * (1.0f / 127.0f);
  int o[4];
#pragma unroll
  for (int i = 0; i < 4; ++i) {
    int q0 = __float2int_rn(v[i][0] * rcp);
    int q1 = __float2int_rn(v[i][1] * rcp);
    int q2 = __float2int_rn(v[i][2] * rcp);
    int q3 = __float2int_rn(v[i][3] * rcp);
    o[i] = (q0 & 255) | ((q1 & 255) << 8) | ((q2 & 255) << 16) | (q3 << 24);
  }
  int4v ov = {o[0], o[1], o[2], o[3]};
  ((int4v*)(xq + (size_t)row * Kdim))[t] = ov;
}

// ---- q (int32 codes 0..126) -> i8 ------------------------------------------
__global__ void cvt_q_i8(const int* __restrict__ q,
                         signed char* __restrict__ qq, int n16) {
  int i = blockIdx.x * blockDim.x + threadIdx.x;
  const int stride = gridDim.x * blockDim.x;
  for (; i < n16; i += stride) {
    const int4v* p = (const int4v*)q + i * 4;
    int o[4];
#pragma unroll
    for (int k = 0; k < 4; ++k) {
      int4v w = p[k];
      o[k] = w[0] | (w[1] << 8) | (w[2] << 16) | (w[3] << 24);
    }
    int4v ov = {o[0], o[1], o[2], o[3]};
    ((int4v*)qq)[i] = ov;
  }
}

// ---- 256x256 i8 GEMM, NO-LDS / NO-BARRIER: C = (A*B^T)*srow*wscale ---------
// 8 waves (2Mx4N), wave tile 128x64. Frag layout = R8's logical LDS layout
// read straight from global (B^T): lane l of frag (i):
//   A row = brow + wm*128 + i*16 + (l&15), bytes [u*64 + (l>>4)*16, +16)
//   B row = bcol + wn*64  + n*16 + (l&15), same K bytes.
// Per-tile: 12 global b128 -> regs (E/O double-buffer), 32 MFMA. No sync.
__global__ __launch_bounds__(512, 2) void gemm_i8(
    const signed char* __restrict__ A, const signed char* __restrict__ B,
    float* __restrict__ C, const float* __restrict__ srow,
    const float* __restrict__ scale_p) {
  const int tid = threadIdx.x;
  const int wid = tid >> 6, lane = tid & 63;
  const int fr = lane & 15;
  const int kg = lane >> 4;  // k-group 0..3

  const int bid = blockIdx.x;
  const int swz = (bid & 7) * (NWG / 8) + (bid >> 3);
  const int mt = swz / NT_N, ntl = swz % NT_N;
  const int brow = mt * BM, bcol = ntl * BN;

  const int wm = wid >> 2, wn = wid & 3;  // 2Mx4N, wave tile 128x64

  // Per-lane base pointers (row + k-subgroup fixed; tile adds u*64 bytes).
  const signed char* pa = A + (size_t)(brow + wm * 128 + fr) * Kdim + kg * 16;
  const signed char* pb = B + (size_t)(bcol + wn * 64 + fr) * Kdim + kg * 16;

  auto loadT = [&](int4v* a, int4v* b, int t) {
    const size_t off = (size_t)t * BK;
#pragma unroll
    for (int n = 0; n < 4; ++n)
      b[n] = *(const int4v*)(pb + (size_t)n * 16 * Kdim + off);
#pragma unroll
    for (int i = 0; i < 8; ++i)
      a[i] = *(const int4v*)(pa + (size_t)i * 16 * Kdim + off);
  };

  int4v acc[8][4] = {};  // [i][n]; row = wm*128 + i*16

  auto mma32 = [&](const int4v* a, const int4v* b) {
    __builtin_amdgcn_s_setprio(1);
#pragma unroll
    for (int i = 0; i < 8; ++i)
#pragma unroll
      for (int n = 0; n < 4; ++n)
        acc[i][n] = __builtin_amdgcn_mfma_i32_16x16x64_i8(
            a[i], b[n], acc[i][n], 0, 0, 0);
    __builtin_amdgcn_s_setprio(0);
  };

  // E/O reg sets (static indexing — rule #20).
  int4v aE[8], bE[4], aO[8], bO[4];

  loadT(aE, bE, 0);
  for (int u = 0; u < NTILES; u += 2) {
    loadT(aO, bO, u + 1);  // issue next-tile loads BEFORE consuming current
    mma32(aE, bE);         // compiler places counted vmcnt before next use
    const int t2 = (u + 2 < NTILES) ? u + 2 : NTILES - 1;  // clamped tail
    loadT(aE, bE, t2);     // (u=62: redundant reload of 63, never consumed)
    mma32(aO, bO);
  }

  // Epilogue: D layout col=lane&15, row=(lane>>4)*4+j (dtype-independent).
  const float sw = *scale_p;
  const int col0 = bcol + wn * 64 + fr;
  const int rb = (lane >> 4) * 4;
#pragma unroll
  for (int i = 0; i < 8; ++i)
#pragma unroll
    for (int j = 0; j < 4; ++j) {
      const int row = brow + wm * 128 + i * 16 + rb + j;
      const float f = srow[row] * sw;
#pragma unroll
      for (int n = 0; n < 4; ++n)
        C[(size_t)row * Ndim + (col0 + n * 16)] = (float)acc[i][n][j] * f;
    }
}

extern "C" void kernel_launch(void* const* d_in, const int* in_sizes, int n_in,
                              void* d_out, int out_size, void* d_ws,
                              size_t ws_size, hipStream_t stream) {
  const float* x = (const float*)d_in[0];
  const int* q = (const int*)d_in[1];
  const float* scale = (const float*)d_in[2];
  float* out = (float*)d_out;

  signed char* xq = (signed char*)d_ws;                 // 33.5 MB
  signed char* qq = xq + (size_t)Mdim * Kdim;           // 16.8 MB
  float* sr = (float*)(qq + (size_t)Ndim * Kdim);       // 32 KB
  const size_t ws_needed =
      (size_t)Mdim * Kdim + (size_t)Ndim * Kdim + Mdim * sizeof(float);
  if (ws_size < ws_needed) return;

  quant_x_i8<<<Mdim, 256, 0, stream>>>(x, xq, sr);
  cvt_q_i8<<<2048, 256, 0, stream>>>(q, qq, (Ndim * Kdim) / 16);
  gemm_i8<<<NWG, 512, 0, stream>>>(xq, qq, out, sr, scale);
}

// Round 14
// 203.101 us; speedup vs baseline: 4.0861x; 1.9991x over previous
//
#include <hip/hip_runtime.h>

// out[8192,4096] = x[8192,4096] @ (q[4096,4096]*scale)^T
// INT8 path (R7/R8-proven, absmax 216): per-row quant x -> i8, exact i8
// weights, fp32 epilogue scale.
// R14 = R8's exact schedule/staging/swizzle (ring-4 slots, stage distance 3,
// barrier-separated WAR, counted vmcnt(4), reg-double-buffered frags) with
// ONE change: mfma_i32_32x32x32_i8 (4404 vs 3944 TOPS ceiling, half the
// MFMA instruction count, same LDS bytes). Stored LDS layout unchanged —
// the staging involution phys16Bslot = s ^ ((row>>1)&3) is read-compatible
// with the 32-row fragment pattern (banks {0,16,4,20,8,24,12,28} per 8-lane
// group — conflict-free, same derivation as R7/R8's measured 0).

typedef __attribute__((ext_vector_type(4))) int int4v;
typedef __attribute__((ext_vector_type(16))) int i32x16;
typedef __attribute__((ext_vector_type(4))) float float4v;

constexpr int Mdim = 8192, Ndim = 4096, Kdim = 4096;
constexpr int BM = 256, BN = 256, BK = 64;
constexpr int NT_N = Ndim / BN;                 // 16
constexpr int NWG = (Mdim / BM) * (Ndim / BN);  // 512 (%8==0)
constexpr int NTILES = Kdim / BK;               // 64

#define GLOAD16(gp, lp)                                                      \
  __builtin_amdgcn_global_load_lds(                                          \
      (const __attribute__((address_space(1))) void*)(gp),                   \
      (__attribute__((address_space(3))) void*)(lp), 16, 0, 0)
#define FENCE() asm volatile("" ::: "memory")
#define BARRIER()                      \
  do {                                 \
    FENCE();                           \
    __builtin_amdgcn_s_barrier();      \
    FENCE();                           \
  } while (0)
#define WAIT_VM(n) asm volatile("s_waitcnt vmcnt(" #n ")" ::: "memory")

// ---- x -> i8, per-row scale ------------------------------------------------
__global__ void quant_x_i8(const float* __restrict__ x,
                           signed char* __restrict__ xq,
                           float* __restrict__ sr) {
  const int row = blockIdx.x;
  const int t = threadIdx.x;  // 256 threads, 16 floats each
  const float4v* px = (const float4v*)(x + (size_t)row * Kdim);
  float4v v[4];
  float am = 0.f;
#pragma unroll
  for (int i = 0; i < 4; ++i) {
    v[i] = px[t * 4 + i];
#pragma unroll
    for (int j = 0; j < 4; ++j) am = fmaxf(am, fabsf(v[i][j]));
  }
#pragma unroll
  for (int off = 32; off; off >>= 1) am = fmaxf(am, __shfl_xor(am, off));
  __shared__ float wmx[4];
  if ((t & 63) == 0) wmx[t >> 6] = am;
  __syncthreads();
  am = fmaxf(fmaxf(wmx[0], wmx[1]), fmaxf(wmx[2], wmx[3]));
  const float rcp = am > 0.f ? 127.0f / am : 0.f;
  if (t == 0) sr[row] = am * (1.0f / 127.0f);
  int o[4];
#pragma unroll
  for (int i = 0; i < 4; ++i) {
    int q0 = __float2int_rn(v[i][0] * rcp);
    int q1 = __float2int_rn(v[i][1] * rcp);
    int q2 = __float2int_rn(v[i][2] * rcp);
    int q3 = __float2int_rn(v[i][3] * rcp);
    o[i] = (q0 & 255) | ((q1 & 255) << 8) | ((q2 & 255) << 16) | (q3 << 24);
  }
  int4v ov = {o[0], o[1], o[2], o[3]};
  ((int4v*)(xq + (size_t)row * Kdim))[t] = ov;
}

// ---- q (int32 codes 0..126) -> i8 ------------------------------------------
__global__ void cvt_q_i8(const int* __restrict__ q,
                         signed char* __restrict__ qq, int n16) {
  int i = blockIdx.x * blockDim.x + threadIdx.x;
  const int stride = gridDim.x * blockDim.x;
  for (; i < n16; i += stride) {
    const int4v* p = (const int4v*)q + i * 4;
    int o[4];
#pragma unroll
    for (int k = 0; k < 4; ++k) {
      int4v w = p[k];
      o[k] = w[0] | (w[1] << 8) | (w[2] << 16) | (w[3] << 24);
    }
    int4v ov = {o[0], o[1], o[2], o[3]};
    ((int4v*)qq)[i] = ov;
  }
}

// ---- 256x256 i8 GEMM, R8 schedule + 32x32x32 MFMA --------------------------
// LDS: ring-4 slots x (A 16 KB + B 16 KB) = 128 KiB. Rows 64 B.
// Body u (one barrier per tile, R8-identical hazard proof):
//   rd 12 b128: frags of tile u+1 (slot (u+1)%4) -> NXT regs
//   stage4: tile min(u+3,63) -> slot (u+3)%4    [WAR: last read body u-1,
//     drained before that body's MFMAs -> its barrier -> this stage]
//   16 MFMA 32x32x32 on CUR regs (pure reg)
//   vmcnt(4)  [forces stage(u+2), read next body]; barrier
__global__ __launch_bounds__(512, 2) void gemm_i8(
    const signed char* __restrict__ A, const signed char* __restrict__ B,
    float* __restrict__ C, const float* __restrict__ srow,
    const float* __restrict__ scale_p) {
  __shared__ signed char sA[4][BM * BK];  // 64 KB
  __shared__ signed char sB[4][BN * BK];  // 64 KB

  const int tid = threadIdx.x;
  const int wid = tid >> 6, lane = tid & 63;
  const int r32 = lane & 31;   // frag row 0..31
  const int kh = lane >> 5;    // k-half 0..1 (16B each within a 32B k-step)
  const int rsw = (r32 >> 1) & 3;  // stored-layout involution term

  const int bid = blockIdx.x;
  const int swz = (bid & 7) * (NWG / 8) + (bid >> 3);
  const int mt = swz / NT_N, ntl = swz % NT_N;
  const int brow = mt * BM, bcol = ntl * BN;

  const int wm = wid >> 2, wn = wid & 3;  // 2Mx4N, wave tile 128x64

  // Staging (byte-identical to R8): issue j covers phys bytes
  // [j*8192 + wid*1024 + lane*16, +16): row = j*128 + wid*16 + (lane>>2),
  // src col = ((lane&3) ^ ((lane>>3)&3)) * 16.
  const int strow = wid * 16 + (lane >> 2);
  const int stcol = (((lane & 3) ^ ((lane >> 3) & 3)) << 4);
  const signed char* gA[2];
  const signed char* gB[2];
#pragma unroll
  for (int j = 0; j < 2; ++j) {
    gA[j] = A + (size_t)(brow + j * 128 + strow) * Kdim + stcol;
    gB[j] = B + (size_t)(bcol + j * 128 + strow) * Kdim + stcol;
  }

  auto stage4 = [&](int slot, int t) {
#pragma unroll
    for (int j = 0; j < 2; ++j)
      GLOAD16(gA[j] + t * BK, &sA[slot][j * 8192 + wid * 1024]);
#pragma unroll
    for (int j = 0; j < 2; ++j)
      GLOAD16(gB[j] + t * BK, &sB[slot][j * 8192 + wid * 1024]);
  };
  // A frag [mi][ks] (mi 0..3, ks 0..1): row = wm*128 + mi*32 + r32,
  // logical 16B-slot s = ks*2 + kh, phys col = (s ^ rsw) << 4.
  auto loadA8 = [&](int4v* af, int sl) {
#pragma unroll
    for (int mi = 0; mi < 4; ++mi)
#pragma unroll
      for (int ks = 0; ks < 2; ++ks)
        af[mi * 2 + ks] = *(const int4v*)(const void*)&sA[sl]
            [(wm * 128 + mi * 32 + r32) * BK + (((ks * 2 + kh) ^ rsw) << 4)];
  };
  auto loadB4 = [&](int4v* bf, int sl) {
#pragma unroll
    for (int nj = 0; nj < 2; ++nj)
#pragma unroll
      for (int ks = 0; ks < 2; ++ks)
        bf[nj * 2 + ks] = *(const int4v*)(const void*)&sB[sl]
            [(wn * 64 + nj * 32 + r32) * BK + (((ks * 2 + kh) ^ rsw) << 4)];
  };

  i32x16 acc[4][2] = {};  // [mi][nj]; 128 acc regs

  auto mma16 = [&](const int4v* af, const int4v* bf) {
    __builtin_amdgcn_s_setprio(1);
#pragma unroll
    for (int mi = 0; mi < 4; ++mi)
#pragma unroll
      for (int nj = 0; nj < 2; ++nj)
#pragma unroll
        for (int ks = 0; ks < 2; ++ks)
          acc[mi][nj] = __builtin_amdgcn_mfma_i32_32x32x32_i8(
              af[mi * 2 + ks], bf[nj * 2 + ks], acc[mi][nj], 0, 0, 0);
    __builtin_amdgcn_s_setprio(0);
  };

  // Even/odd cross-tile prefetch sets (static indexing — rule #20).
  int4v aE[8], bE[4], aO[8], bO[4];

  auto body = [&](int u, const int4v* aC, const int4v* bC, int4v* aN,
                  int4v* bN) {
    const int sn = (u + 1) & 3;
    const int st = (u + 3) & 3;
    const int t3 = (u + 3 < NTILES) ? u + 3 : NTILES - 1;  // clamped tail
    loadB4(bN, sn);
    loadA8(aN, sn);
    stage4(st, t3);
    mma16(aC, bC);
    WAIT_VM(4);  // forces stage(u+2); stage(u+3) stays in flight
    BARRIER();
  };

  // Prologue (R8-identical): tiles 0,1,2 -> slots 0,1,2.
  stage4(0, 0);
  stage4(1, 1);
  stage4(2, 2);
  WAIT_VM(8);  // slot 0 landed (this wave)
  BARRIER();   // ... all waves
  loadB4(bE, 0);
  loadA8(aE, 0);
  WAIT_VM(4);  // slot 1 landed
  BARRIER();

  for (int u = 0; u < NTILES; u += 2) {
    body(u, aE, bE, aO, bO);      // tile u:   cur=E, prefetch->O
    body(u + 1, aO, bO, aE, bE);  // tile u+1: cur=O, prefetch->E
  }

  WAIT_VM(0);  // drain clamped trailing stages before exit

  // Epilogue: 32x32 D layout col=lane&31, row=(reg&3)+8*(reg>>2)+4*(lane>>5)
  // [m74/m101-verified, dtype-independent].
  const float sw = *scale_p;
  const int col0 = bcol + wn * 64 + r32;
#pragma unroll
  for (int mi = 0; mi < 4; ++mi)
#pragma unroll
    for (int reg = 0; reg < 16; ++reg) {
      const int row =
          brow + wm * 128 + mi * 32 + (reg & 3) + 8 * (reg >> 2) + 4 * kh;
      const float f = srow[row] * sw;
#pragma unroll
      for (int nj = 0; nj < 2; ++nj)
        C[(size_t)row * Ndim + (col0 + nj * 32)] =
            (float)acc[mi][nj][reg] * f;
    }
}

extern "C" void kernel_launch(void* const* d_in, const int* in_sizes, int n_in,
                              void* d_out, int out_size, void* d_ws,
                              size_t ws_size, hipStream_t stream) {
  const float* x = (const float*)d_in[0];
  const int* q = (const int*)d_in[1];
  const float* scale = (const float*)d_in[2];
  float* out = (float*)d_out;

  signed char* xq = (signed char*)d_ws;                 // 33.5 MB
  signed char* qq = xq + (size_t)Mdim * Kdim;           // 16.8 MB
  float* sr = (float*)(qq + (size_t)Ndim * Kdim);       // 32 KB
  const size_t ws_needed =
      (size_t)Mdim * Kdim + (size_t)Ndim * Kdim + Mdim * sizeof(float);
  if (ws_size < ws_needed) return;

  quant_x_i8<<<Mdim, 256, 0, stream>>>(x, xq, sr);
  cvt_q_i8<<<2048, 256, 0, stream>>>(q, qq, (Ndim * Kdim) / 16);
  gemm_i8<<<NWG, 512, 0, stream>>>(xq, qq, out, sr, scale);
}

// Round 16
// 189.597 us; speedup vs baseline: 4.3771x; 1.0712x over previous
//
#include <hip/hip_runtime.h>

// out[8192,4096] = x[8192,4096] @ (q[4096,4096]*scale)^T
// INT8 path (R7/R8-proven, absmax 216): per-row quant x -> i8, exact i8
// weights, mfma_i32_16x16x64_i8, fp32 epilogue scale.
// R16 = R15 (LDS-A + direct-global-B from fragment-tiled qq) with the
// PROLOGUE RACE FIXED: WAIT_VM(4) forces ALL three prologue A-stages before
// the loop (R15's WAIT_VM(8) left stageA(1) in flight while body(0) ds_read
// slot 1 -> graph-replay divergence).

typedef __attribute__((ext_vector_type(4))) int int4v;
typedef __attribute__((ext_vector_type(4))) float float4v;

constexpr int Mdim = 8192, Ndim = 4096, Kdim = 4096;
constexpr int BM = 256, BN = 256, BK = 64;
constexpr int NT_N = Ndim / BN;                 // 16
constexpr int NWG = (Mdim / BM) * (Ndim / BN);  // 512 (%8==0)
constexpr int NTILES = Kdim / BK;               // 64
constexpr int KT = Kdim / 64;                   // 64 k-tiles (B layout)

#define GLOAD16(gp, lp)                                                      \
  __builtin_amdgcn_global_load_lds(                                          \
      (const __attribute__((address_space(1))) void*)(gp),                   \
      (__attribute__((address_space(3))) void*)(lp), 16, 0, 0)
#define FENCE() asm volatile("" ::: "memory")
#define BARRIER()                      \
  do {                                 \
    FENCE();                           \
    __builtin_amdgcn_s_barrier();      \
    FENCE();                           \
  } while (0)
#define WAIT_VM(n) asm volatile("s_waitcnt vmcnt(" #n ")" ::: "memory")

// ---- x -> i8, per-row scale (unchanged, R7-proven) -------------------------
__global__ void quant_x_i8(const float* __restrict__ x,
                           signed char* __restrict__ xq,
                           float* __restrict__ sr) {
  const int row = blockIdx.x;
  const int t = threadIdx.x;  // 256 threads, 16 floats each
  const float4v* px = (const float4v*)(x + (size_t)row * Kdim);
  float4v v[4];
  float am = 0.f;
#pragma unroll
  for (int i = 0; i < 4; ++i) {
    v[i] = px[t * 4 + i];
#pragma unroll
    for (int j = 0; j < 4; ++j) am = fmaxf(am, fabsf(v[i][j]));
  }
#pragma unroll
  for (int off = 32; off; off >>= 1) am = fmaxf(am, __shfl_xor(am, off));
  __shared__ float wmx[4];
  if ((t & 63) == 0) wmx[t >> 6] = am;
  __syncthreads();
  am = fmaxf(fmaxf(wmx[0], wmx[1]), fmaxf(wmx[2], wmx[3]));
  const float rcp = am > 0.f ? 127.0f / am : 0.f;
  if (t == 0) sr[row] = am * (1.0f / 127.0f);
  int o[4];
#pragma unroll
  for (int i = 0; i < 4; ++i) {
    int q0 = __float2int_rn(v[i][0] * rcp);
    int q1 = __float2int_rn(v[i][1] * rcp);
    int q2 = __float2int_rn(v[i][2] * rcp);
    int q3 = __float2int_rn(v[i][3] * rcp);
    o[i] = (q0 & 255) | ((q1 & 255) << 8) | ((q2 & 255) << 16) | (q3 << 24);
  }
  int4v ov = {o[0], o[1], o[2], o[3]};
  ((int4v*)(xq + (size_t)row * Kdim))[t] = ov;
}

// ---- q (int32 codes) -> i8, FRAGMENT-TILED layout --------------------------
// qq[tile = nb*KT + kb][lane][16B]: lane l holds B[nb*16 + (l&15)]
// [kb*64 + (l>>4)*16 .. +16]. One wave per tile; writes 1KB contiguous.
__global__ void cvt_q_i8_tiled(const int* __restrict__ q,
                               signed char* __restrict__ qq) {
  const int tile = blockIdx.x * 4 + (threadIdx.x >> 6);  // 4 waves/block
  const int lane = threadIdx.x & 63;
  const int n = (tile / KT) * 16 + (lane & 15);
  const int k0 = (tile % KT) * 64 + (lane >> 4) * 16;
  const int4v* src = (const int4v*)(q + (size_t)n * Kdim + k0);
  int o[4];
#pragma unroll
  for (int i = 0; i < 4; ++i) {
    int4v w = src[i];
    o[i] = w[0] | (w[1] << 8) | (w[2] << 16) | (w[3] << 24);
  }
  int4v ov = {o[0], o[1], o[2], o[3]};
  ((int4v*)qq)[(size_t)tile * 64 + lane] = ov;
}

// ---- 256x256 i8 GEMM, LDS-A + direct-global-B ------------------------------
// LDS: ring-4 A slots x 16 KB = 64 KiB. A staging/swizzle byte-identical to
// R8 (measured 0 conflicts). B: 4 coalesced 1KB frag loads per wave per tile.
//
// vmcnt ledger (reorder-robust: stage(u+2) is always the OLDEST outstanding
// at each body-end wait, so it is forced under any legal intra-body load
// reordering):
//   prologue: issue stage(0),stage(1),stage(2),B(0) = 10; WAIT_VM(4) forces
//     all three stages (slots 0,1,2); leaves B(0) (compiler-waited before
//     its consuming MFMA). barrier.
//   body u: entry outstanding ~{stage(u+2):2 and/or forced-B leftovers};
//     issues B(u+1):4 + stage(u+3):2; WAIT_VM(2) leaves <=2 newest ->
//     stage(u+2) (oldest) is forced -> body u+1's ds_read of slot (u+2) safe.
//   WAR: stage slot (u+3)%4 last ds_read in body u-2, lgkm-drained before
//     body u-1's MFMA -> its barrier -> this stage (cross-wave via barrier).
__global__ __launch_bounds__(512, 2) void gemm_i8(
    const signed char* __restrict__ A, const signed char* __restrict__ Bt,
    float* __restrict__ C, const float* __restrict__ srow,
    const float* __restrict__ scale_p) {
  __shared__ signed char sA[4][BM * BK];  // 64 KiB

  const int tid = threadIdx.x;
  const int wid = tid >> 6, lane = tid & 63;
  const int fr = lane & 15;
  const int kg = lane >> 4;
  const int kx = ((kg ^ ((fr >> 1) & 3)) << 4);  // R8's measured-0 swizzle

  const int bid = blockIdx.x;
  const int swz = (bid & 7) * (NWG / 8) + (bid >> 3);
  const int mt = swz / NT_N, ntl = swz % NT_N;
  const int brow = mt * BM, bcol = ntl * BN;

  const int wm = wid >> 2, wn = wid & 3;  // 2Mx4N, wave tile 128x64

  // A staging (byte-identical to R8): issue j covers phys bytes
  // [j*8192 + wid*1024 + lane*16): row = j*128 + wid*16 + (lane>>2),
  // src col = ((lane&3) ^ ((lane>>3)&3)) * 16.
  const int strow = wid * 16 + (lane >> 2);
  const int stcol = (((lane & 3) ^ ((lane >> 3) & 3)) << 4);
  const signed char* gA[2];
#pragma unroll
  for (int j = 0; j < 2; ++j)
    gA[j] = A + (size_t)(brow + j * 128 + strow) * Kdim + stcol;

  auto stageA2 = [&](int slot, int t) {
#pragma unroll
    for (int j = 0; j < 2; ++j)
      GLOAD16(gA[j] + t * BK, &sA[slot][j * 8192 + wid * 1024]);
  };
  auto loadA8 = [&](int4v* af, int sl) {
#pragma unroll
    for (int i = 0; i < 8; ++i)
      af[i] = *(const int4v*)(const void*)&sA[sl]
                  [(wm * 128 + i * 16 + fr) * BK + kx];
  };
  // B frags direct from tiled global: frag n, tile t ->
  //   qq int4v index ((bcol/16 + wn*4 + n)*KT + t)*64 + lane.
  const int4v* Bw4 =
      (const int4v*)Bt + ((size_t)(bcol / 16) + wn * 4) * KT * 64 + lane;
  auto loadB4g = [&](int4v* bf, int t) {
#pragma unroll
    for (int n = 0; n < 4; ++n)
      bf[n] = Bw4[((size_t)n * KT + t) * 64];
  };

  int4v acc[8][4] = {};  // [i][n]; row = wm*128 + i*16

  auto mma32 = [&](const int4v* af, const int4v* bf) {
    __builtin_amdgcn_s_setprio(1);
#pragma unroll
    for (int i = 0; i < 8; ++i)
#pragma unroll
      for (int n = 0; n < 4; ++n)
        acc[i][n] = __builtin_amdgcn_mfma_i32_16x16x64_i8(
            af[i], bf[n], acc[i][n], 0, 0, 0);
    __builtin_amdgcn_s_setprio(0);
  };

  // Even/odd cross-tile prefetch sets (static indexing — rule #20).
  int4v aE[8], bE[4], aO[8], bO[4];

  auto body = [&](int u, const int4v* aC, const int4v* bC, int4v* aN,
                  int4v* bN) {
    const int sn = (u + 1) & 3;
    const int tB = (u + 1 < NTILES) ? u + 1 : NTILES - 1;  // clamped
    const int st = (u + 3) & 3;
    const int t3 = (u + 3 < NTILES) ? u + 3 : NTILES - 1;  // clamped tail
    loadB4g(bN, tB);
    loadA8(aN, sn);
    stageA2(st, t3);
    mma32(aC, bC);
    WAIT_VM(2);  // forces stage(u+2) (oldest); next body's ds_read safe
    BARRIER();
  };

  // Prologue: A tiles 0,1,2 -> slots 0,1,2; B tile 0 -> regs.
  stageA2(0, 0);
  stageA2(1, 1);
  stageA2(2, 2);
  loadB4g(bE, 0);
  WAIT_VM(4);  // R16 FIX: forces ALL prologue stages (slots 0,1,2);
               // leaves only B(0), compiler-waited before its MFMA use
  BARRIER();
  loadA8(aE, 0);

  for (int u = 0; u < NTILES; u += 2) {
    body(u, aE, bE, aO, bO);      // tile u:   cur=E, prefetch->O
    body(u + 1, aO, bO, aE, bE);  // tile u+1: cur=O, prefetch->E
  }

  WAIT_VM(0);  // drain trailing clamped stages before exit

  // Epilogue: D layout col=lane&15, row=(lane>>4)*4+j (dtype-independent).
  const float sw = *scale_p;
  const int col0 = bcol + wn * 64 + fr;
  const int rb = (lane >> 4) * 4;
#pragma unroll
  for (int i = 0; i < 8; ++i)
#pragma unroll
    for (int j = 0; j < 4; ++j) {
      const int row = brow + wm * 128 + i * 16 + rb + j;
      const float f = srow[row] * sw;
#pragma unroll
      for (int n = 0; n < 4; ++n)
        C[(size_t)row * Ndim + (col0 + n * 16)] = (float)acc[i][n][j] * f;
    }
}

extern "C" void kernel_launch(void* const* d_in, const int* in_sizes, int n_in,
                              void* d_out, int out_size, void* d_ws,
                              size_t ws_size, hipStream_t stream) {
  const float* x = (const float*)d_in[0];
  const int* q = (const int*)d_in[1];
  const float* scale = (const float*)d_in[2];
  float* out = (float*)d_out;

  signed char* xq = (signed char*)d_ws;                 // 33.5 MB
  signed char* qq = xq + (size_t)Mdim * Kdim;           // 16.8 MB (tiled)
  float* sr = (float*)(qq + (size_t)Ndim * Kdim);       // 32 KB
  const size_t ws_needed =
      (size_t)Mdim * Kdim + (size_t)Ndim * Kdim + Mdim * sizeof(float);
  if (ws_size < ws_needed) return;

  quant_x_i8<<<Mdim, 256, 0, stream>>>(x, xq, sr);
  // (Ndim/16)*(Kdim/64) = 16384 tiles, 4 waves/block -> 4096 blocks exact.
  cvt_q_i8_tiled<<<4096, 256, 0, stream>>>(q, qq);
  gemm_i8<<<NWG, 512, 0, stream>>>(xq, qq, out, sr, scale);
}